// Round 7
// baseline (138.556 us; speedup 1.0000x reference)
//
#include <hip/hip_runtime.h>

// PolyAttn collapse: a = s^4/|s^4| == 1.0 identically, so
//   out[b,n,:] = vsum[b,:] @ w_o  (independent of n, q, k, alpha),
//   vsum[b,:]  = (sum_n x[b,n,:]) @ w_qkv[:, 2H:3H].
// R7: 2-node graph. Node cost model (R2/R5/R6 fits) ~4us/node -> cut nodes.
// node2 = producer-consumer: 64 producer blocks compute orow (atomics),
// bump a counter; all 512 blocks then broadcast. Not a grid barrier:
// producers never wait; all blocks co-resident (22KB LDS, 256 thr).

#define B_ 4
#define N_ 2048
#define D_ 1024
#define H_ 1024
#define H3_ 3072
#define NPROD_ 64
#define NBC_ 512

// padded LDS xsum: d -> d + (d>>4); per-b stride 1088 floats.
#define XS(b, d) s_xs[(b) * 1088 + (d) + ((d) >> 4)]

// ws: part[4][16][1024] f (256 KB) | orow[4][1024] f | ctrl[1] i

// ---- kA: 1024 work blocks (b, ng, dq) + 4 zero orow + 1 zeros ctrl ---------
__global__ __launch_bounds__(256) void kA(const float* __restrict__ x,
                                          float4* __restrict__ part4,
                                          float4* __restrict__ orow4,
                                          int* __restrict__ ctrl) {
    const int blk = blockIdx.x;
    const int t   = threadIdx.x;
    __shared__ float4 s4[16][16];
    if (blk < 1024) {
        const int b  = blk >> 8;           // 4
        const int ng = (blk >> 4) & 15;    // 16 groups of 128 rows
        const int dq = blk & 15;           // 16 slices of 64 floats
        const int d4 = t & 15;
        const int rr = t >> 4;             // 16 row streams x 8 rows
        const float4* x4 = reinterpret_cast<const float4*>(x);
        size_t base = ((size_t)b * N_ + ng * 128 + rr * 8) * (D_ / 4) + dq * 16 + d4;
        float4 acc = make_float4(0.f, 0.f, 0.f, 0.f);
#pragma unroll 8
        for (int i = 0; i < 8; ++i) {
            float4 v = x4[base + (size_t)i * (D_ / 4)];
            acc.x += v.x; acc.y += v.y; acc.z += v.z; acc.w += v.w;
        }
        s4[rr][d4] = acc;
        __syncthreads();
        if (t < 16) {
            float4 a = s4[0][t];
#pragma unroll 15
            for (int r = 1; r < 16; ++r) {
                float4 v = s4[r][t];
                a.x += v.x; a.y += v.y; a.z += v.z; a.w += v.w;
            }
            part4[((size_t)(b * 16 + ng)) * 256 + dq * 16 + t] = a;
        }
    } else if (blk < 1028) {
        orow4[(blk - 1024) * 256 + t] = make_float4(0.f, 0.f, 0.f, 0.f);
    } else if (t == 0) {
        *ctrl = 0;
    }
}

// ---- kBC: 512 blocks x 256 thr ---------------------------------------------
// blocks 0..63: produce orow chunk [h0,h0+16); all blocks: broadcast 16 rows.
__global__ __launch_bounds__(256) void kBC(const float4* __restrict__ part4,
                                           const float* __restrict__ w_qkv,
                                           const float* __restrict__ w_o,
                                           float* __restrict__ orow,
                                           int* __restrict__ ctrl,
                                           float* __restrict__ out) {
    const int blk = blockIdx.x;
    const int tid = threadIdx.x;
    __shared__ float s_xs[4 * 1088];      // 17.4 KB; reused as orow copy later
    __shared__ float s_red[4 * 16 * 16];  // [b][h][dg] 4 KB
    __shared__ float s_vs[64];            // [b][h]

    if (blk < NPROD_) {
        const int h0 = blk * 16;
        // step 1: xsum[b][d] = sum_ng part[b][ng][d]   (256 KB, L2-served)
#pragma unroll
        for (int k = 0; k < 4; ++k) {
            const int col = tid + k * 256;            // (b, d4)
            const int b = col >> 8, d4 = col & 255;
            const float4* p = part4 + (size_t)b * 16 * 256 + d4;
            float4 acc = make_float4(0.f, 0.f, 0.f, 0.f);
#pragma unroll
            for (int g = 0; g < 16; ++g) {
                float4 v = p[(size_t)g * 256];
                acc.x += v.x; acc.y += v.y; acc.z += v.z; acc.w += v.w;
            }
            const int d = d4 * 4;
            XS(b, d + 0) = acc.x;
            XS(b, d + 1) = acc.y;
            XS(b, d + 2) = acc.z;
            XS(b, d + 3) = acc.w;
        }
        __syncthreads();
        // step 2: vs[b][h] = sum_d xsum[b][d]*Wv[d,h0+h]; 256 = 16 dg x 16 h
        {
            const int h  = tid & 15;
            const int dg = tid >> 4;
            const float* wv = w_qkv + 2 * H_ + h0 + h;
            float a0 = 0.f, a1 = 0.f, a2 = 0.f, a3 = 0.f;
#pragma unroll 4
            for (int i = 0; i < 64; ++i) {
                const int d = dg * 64 + i;
                const float w = wv[(size_t)d * H3_];
                a0 += XS(0, d) * w;
                a1 += XS(1, d) * w;
                a2 += XS(2, d) * w;
                a3 += XS(3, d) * w;
            }
            s_red[(0 * 16 + h) * 16 + dg] = a0;
            s_red[(1 * 16 + h) * 16 + dg] = a1;
            s_red[(2 * 16 + h) * 16 + dg] = a2;
            s_red[(3 * 16 + h) * 16 + dg] = a3;
        }
        __syncthreads();
        if (tid < 64) {                    // (b,h): fold 16 dg
            float v = 0.f;
#pragma unroll
            for (int k = 0; k < 16; ++k) v += s_red[tid * 16 + k];
            s_vs[tid] = v;
        }
        __syncthreads();
        // step 3: orow[b][d] += sum_j vs[b][j] * Wo[h0+j][d]  (coalesced in d)
#pragma unroll
        for (int k = 0; k < 16; ++k) {
            const int idx = tid + k * 256;            // (b, d)
            const int b = idx >> 10, d = idx & 1023;
            float o = 0.f;
#pragma unroll
            for (int j = 0; j < 16; ++j)
                o += s_vs[b * 16 + j] * w_o[(size_t)(h0 + j) * D_ + d];
            atomicAdd(&orow[idx], o);
        }
        __threadfence();
        __syncthreads();
        if (tid == 0)
            __hip_atomic_fetch_add(ctrl, 1, __ATOMIC_ACQ_REL,
                                   __HIP_MEMORY_SCOPE_AGENT);
    }

    // ---- all 512 blocks: wait for orow, then broadcast 16 rows each --------
    if (tid == 0) {
        while (__hip_atomic_load(ctrl, __ATOMIC_ACQUIRE,
                                 __HIP_MEMORY_SCOPE_AGENT) != NPROD_)
            __builtin_amdgcn_s_sleep(32);
    }
    __syncthreads();
    // coherent copy of orow into LDS (reuse s_xs)
#pragma unroll
    for (int k = 0; k < 16; ++k) {
        const int idx = tid + k * 256;
        s_xs[idx] = __hip_atomic_load(orow + idx, __ATOMIC_RELAXED,
                                      __HIP_MEMORY_SCOPE_AGENT);
    }
    __syncthreads();
    {
        float4* out4 = reinterpret_cast<float4*>(out);
        const float4* o4 = reinterpret_cast<const float4*>(s_xs);
#pragma unroll
        for (int r = 0; r < 16; ++r) {
            const int row = blk * 16 + r;             // global row in [0, 8192)
            const int b   = row >> 11;
            out4[(size_t)row * (D_ / 4) + tid] = o4[b * 256 + tid];
        }
    }
}

extern "C" void kernel_launch(void* const* d_in, const int* in_sizes, int n_in,
                              void* d_out, int out_size, void* d_ws, size_t ws_size,
                              hipStream_t stream) {
    const float* x     = (const float*)d_in[0];   // [B, N, D]
    const float* w_qkv = (const float*)d_in[1];   // [D, 3H]
    const float* w_o   = (const float*)d_in[2];   // [H, D]
    // d_in[3] = alpha — provably unused (a == 1 regardless of alpha).
    float* out = (float*)d_out;                   // [B, N, D] fp32

    float* part = (float*)d_ws;                   // 4*16*1024 = 65536 floats
    float* orow = part + (size_t)B_ * 16 * D_;    // 4096 floats
    int*   ctrl = (int*)(orow + B_ * D_);         // 1 int

    kA<<<1029, 256, 0, stream>>>(x, (float4*)part, (float4*)orow, ctrl);
    kBC<<<NBC_, 256, 0, stream>>>((const float4*)part, w_qkv, w_o,
                                  orow, ctrl, out);
}

// Round 8
// 29.276 us; speedup vs baseline: 4.7328x; 4.7328x over previous
//
#include <hip/hip_runtime.h>

// PolyAttn collapse: a = s^4/|s^4| == 1.0 identically, so
//   out[b,n,:] = vsum[b,:] @ w_o  (independent of n, q, k, alpha),
//   vsum[b,:]  = (sum_n x[b,n,:]) @ w_qkv[:, 2H:3H].
// R8 = R6 skeleton (3 nodes; grid barriers ~15us and spin-waits ~100us on
// this 8-XCD part -> banned) + 16x lower atomic contention:
//   kB: 64 blocks, h-chunk 16, atomics into opart[8] (slot=blk&7, 8 writers
//   per address, 262K atomics total); kC folds the 8 slots then broadcasts.

#define B_ 4
#define N_ 2048
#define D_ 1024
#define H_ 1024
#define H3_ 3072

// padded LDS xsum: d -> d + (d>>4); per-b stride 1088 floats.
#define XS(b, d) s_xs[(b) * 1088 + (d) + ((d) >> 4)]

// ws layout (floats): part[4][8][1024] (128 KB) | opart[8][4][1024] (128 KB)

// ---- kA: 512 work blocks (b, ng, dq) + 8 blocks zeroing opart --------------
__global__ __launch_bounds__(256) void kA(const float* __restrict__ x,
                                          float4* __restrict__ part4,
                                          float4* __restrict__ opart4) {
    const int blk = blockIdx.x;
    const int t   = threadIdx.x;
    __shared__ float4 s4[16][16];
    if (blk < 512) {
        const int b  = blk >> 7;
        const int ng = (blk >> 4) & 7;     // 8 groups of 256 rows
        const int dq = blk & 15;           // 16 slices of 64 floats
        const int d4 = t & 15;
        const int rr = t >> 4;             // 16 row streams x 16 rows
        const float4* x4 = reinterpret_cast<const float4*>(x);
        size_t base = ((size_t)b * N_ + ng * 256 + rr * 16) * (D_ / 4) + dq * 16 + d4;
        float4 acc = make_float4(0.f, 0.f, 0.f, 0.f);
#pragma unroll 16
        for (int i = 0; i < 16; ++i) {
            float4 v = x4[base + (size_t)i * (D_ / 4)];
            acc.x += v.x; acc.y += v.y; acc.z += v.z; acc.w += v.w;
        }
        s4[rr][d4] = acc;
        __syncthreads();
        if (t < 16) {
            float4 a = s4[0][t];
#pragma unroll 15
            for (int r = 1; r < 16; ++r) {
                float4 v = s4[r][t];
                a.x += v.x; a.y += v.y; a.z += v.z; a.w += v.w;
            }
            part4[((size_t)(b * 8 + ng)) * 256 + dq * 16 + t] = a;
        }
    } else {
        // zero opart slot (blk-512): 1024 float4s
        float4* dst = opart4 + (size_t)(blk - 512) * 1024;
#pragma unroll
        for (int k = 0; k < 4; ++k)
            dst[t + k * 256] = make_float4(0.f, 0.f, 0.f, 0.f);
    }
}

// ---- kB: 64 blocks x 512 thr; block owns h-chunk [h0, h0+16) ---------------
__global__ __launch_bounds__(512) void kB(const float4* __restrict__ part4,
                                          const float* __restrict__ w_qkv,
                                          const float* __restrict__ w_o,
                                          float* __restrict__ opart) {
    const int tid  = threadIdx.x;
    const int h0   = blockIdx.x * 16;
    const int slot = blockIdx.x & 7;
    __shared__ float s_xs[4 * 1088 + 4];   // padded xsum, 17.4 KB
    __shared__ float s_red[64 * 33];       // [(b*16+h)][dg], stride-33 pad
    __shared__ float s_vs[64];             // [b*16+h]

    // step 1: xsum[b][d] = sum_ng part[b][ng][d]   (128 KB, L2-served)
#pragma unroll
    for (int k = 0; k < 2; ++k) {
        const int task = tid + k * 512;    // (b, d4)
        const int b = task >> 8, d4 = task & 255;
        const float4* p = part4 + (size_t)b * 8 * 256 + d4;
        float4 acc = make_float4(0.f, 0.f, 0.f, 0.f);
#pragma unroll
        for (int g = 0; g < 8; ++g) {
            float4 v = p[(size_t)g * 256];
            acc.x += v.x; acc.y += v.y; acc.z += v.z; acc.w += v.w;
        }
        const int d = d4 * 4;
        XS(b, d + 0) = acc.x;
        XS(b, d + 1) = acc.y;
        XS(b, d + 2) = acc.z;
        XS(b, d + 3) = acc.w;
    }
    __syncthreads();

    // step 2: vs[b][h] = sum_d xsum[b][d] * Wv[d, h0+h];  512 = 32 dg x 16 h
    {
        const int h  = tid & 15;
        const int dg = tid >> 4;
        const float* wv = w_qkv + 2 * H_ + h0 + h;
        float a0 = 0.f, a1 = 0.f, a2 = 0.f, a3 = 0.f;
#pragma unroll 4
        for (int i = 0; i < 32; ++i) {
            const int d = dg * 32 + i;
            const float w = wv[(size_t)d * H3_];
            a0 += XS(0, d) * w;
            a1 += XS(1, d) * w;
            a2 += XS(2, d) * w;
            a3 += XS(3, d) * w;
        }
        s_red[(0 * 16 + h) * 33 + dg] = a0;
        s_red[(1 * 16 + h) * 33 + dg] = a1;
        s_red[(2 * 16 + h) * 33 + dg] = a2;
        s_red[(3 * 16 + h) * 33 + dg] = a3;
    }
    __syncthreads();
    if (tid < 64) {                        // (b,h): fold 32 dg, stride-33 rows
        float v = 0.f;
#pragma unroll
        for (int k = 0; k < 32; ++k) v += s_red[tid * 33 + k];
        s_vs[tid] = v;
    }
    __syncthreads();

    // step 3: opart[slot][b][d] += sum_j vs[b][j] * Wo[h0+j][d]
#pragma unroll
    for (int k = 0; k < 8; ++k) {
        const int idx = tid + k * 512;     // (b, d) over 4096
        const int b = idx >> 10, d = idx & 1023;
        float o = 0.f;
#pragma unroll
        for (int j = 0; j < 16; ++j)
            o += s_vs[b * 16 + j] * w_o[(size_t)(h0 + j) * D_ + d];
        atomicAdd(&opart[(size_t)slot * 4096 + idx], o);
    }
}

// ---- kC: 512 blocks (b, rg): fold 8 slots -> orow[b]; write 16 rows --------
__global__ __launch_bounds__(256) void kC(const float4* __restrict__ opart4,
                                          float* __restrict__ out) {
    const int blk = blockIdx.x;
    const int b = blk >> 7, rg = blk & 127;
    const int t = threadIdx.x;
    __shared__ float4 s_o4[256];
    {
        const float4* p = opart4 + b * 256 + t;
        float4 acc = make_float4(0.f, 0.f, 0.f, 0.f);
#pragma unroll
        for (int s = 0; s < 8; ++s) {
            float4 v = p[(size_t)s * 1024];
            acc.x += v.x; acc.y += v.y; acc.z += v.z; acc.w += v.w;
        }
        s_o4[t] = acc;
    }
    __syncthreads();
    const float4 val = s_o4[t];
    float4* out4 = reinterpret_cast<float4*>(out);
    size_t base = ((size_t)b * N_ + rg * 16) * (D_ / 4) + t;
#pragma unroll 16
    for (int i = 0; i < 16; ++i)
        out4[base + (size_t)i * (D_ / 4)] = val;
}

extern "C" void kernel_launch(void* const* d_in, const int* in_sizes, int n_in,
                              void* d_out, int out_size, void* d_ws, size_t ws_size,
                              hipStream_t stream) {
    const float* x     = (const float*)d_in[0];   // [B, N, D]
    const float* w_qkv = (const float*)d_in[1];   // [D, 3H]
    const float* w_o   = (const float*)d_in[2];   // [H, D]
    // d_in[3] = alpha — provably unused (a == 1 regardless of alpha).
    float* out = (float*)d_out;                   // [B, N, D] fp32

    float* part  = (float*)d_ws;                  // 4*8*1024  = 32768 floats
    float* opart = part + (size_t)B_ * 8 * D_;    // 8*4*1024  = 32768 floats

    kA<<<520, 256, 0, stream>>>(x, (float4*)part, (float4*)opart);
    kB<<<64, 512, 0, stream>>>((const float4*)part, w_qkv, w_o, opart);
    kC<<<512, 256, 0, stream>>>((const float4*)opart, out);
}